// Round 12
// baseline (243.596 us; speedup 1.0000x reference)
//
#include <hip/hip_runtime.h>
#include <hip/hip_bf16.h>
#include <cstdint>

#define NN   8192
#define HID  128

typedef __attribute__((ext_vector_type(8)))  __bf16          bf16x8;
typedef __attribute__((ext_vector_type(16))) float           f32x16;
typedef __attribute__((ext_vector_type(8)))  unsigned short  u16x8;
typedef __attribute__((ext_vector_type(4)))  unsigned short  u16x4;
typedef __attribute__((ext_vector_type(4)))  float           f32x4;

__device__ __forceinline__ float b2f(unsigned short u){
  union { unsigned int i; float f; } v; v.i = ((unsigned int)u) << 16; return v.f;
}
__device__ __forceinline__ unsigned short f2b(float f){
  unsigned int i = __float_as_uint(f);
  unsigned int r = (i + 0x7FFFu + ((i >> 16) & 1u)) >> 16;   // RNE
  return (unsigned short)r;
}
__device__ __forceinline__ void gld_lds16(const void* g, void* l){
  __builtin_amdgcn_global_load_lds((const __attribute__((address_space(1))) unsigned int*)g,
                                   (__attribute__((address_space(3))) unsigned int*)l, 16, 0, 0);
}

// ---------------- dtype detect: bf16 buffers -> flag=1, f32 -> flag=0 ----------------
__global__ __launch_bounds__(256) void k_detect(const unsigned int* __restrict__ a,
                                                int* __restrict__ flag){
  __shared__ int cnt;
  if(threadIdx.x == 0) cnt = 0;
  __syncthreads();
  int c = 0;
  #pragma unroll
  for(int i = 0; i < 16; ++i){
    unsigned int w = a[i * 256 + threadIdx.x];
    c += (((w >> 8) & 0xC0u) == 0u) ? 1 : 0;
  }
  atomicAdd(&cnt, c);
  __syncthreads();
  if(threadIdx.x == 0) *flag = (cnt > 3000) ? 1 : 0;
}

// -------- deg + inv_sqrt_deg, fused f32->bf16 adj convert (one wave per row) --------
__global__ __launch_bounds__(256) void k_degcvt(const void* __restrict__ adjv,
                                                const int* __restrict__ flagp,
                                                float* __restrict__ isd,
                                                unsigned short* __restrict__ adjb){
  const int wid = threadIdx.x >> 6, l = threadIdx.x & 63;
  const int row = blockIdx.x * 4 + wid;
  float s = 0.f;
  if(*flagp){
    const u16x8* rp = (const u16x8*)((const unsigned short*)adjv + (size_t)row * NN);
    #pragma unroll
    for(int it = 0; it < 16; ++it){
      u16x8 v = rp[it * 64 + l];
      #pragma unroll
      for(int j = 0; j < 8; ++j) s += b2f(v[j]);
    }
  } else {
    const f32x4* rp = (const f32x4*)((const float*)adjv + (size_t)row * NN);
    u16x4* wp = (u16x4*)(adjb + (size_t)row * NN);
    #pragma unroll
    for(int it = 0; it < 32; ++it){
      f32x4 v = rp[it * 64 + l];
      s += v[0] + v[1] + v[2] + v[3];
      u16x4 w;
      w[0] = f2b(v[0]); w[1] = f2b(v[1]); w[2] = f2b(v[2]); w[3] = f2b(v[3]);
      wp[it * 64 + l] = w;
    }
  }
  #pragma unroll
  for(int m = 32; m > 0; m >>= 1) s += __shfl_xor(s, m, 64);
  if(l == 0) isd[row] = (s > 0.f) ? rsqrtf(fmaxf(s, 1e-12f)) : 0.f;
}

// ---------------- W transpose to bf16: Wt[l][c][i] = bf16(Ws[l][i][c]) ----------------
__global__ __launch_bounds__(256) void k_wt(const void* __restrict__ Ws,
                                            const int* __restrict__ flagp,
                                            unsigned short* __restrict__ Wt){
  const int x = blockIdx.x * 256 + threadIdx.x;
  const int lyr = x >> 14, rem = x & 16383, i = rem >> 7, c = rem & 127;
  unsigned short u;
  if(*flagp) u = ((const unsigned short*)Ws)[x];
  else       u = f2b(((const float*)Ws)[x]);
  Wt[lyr * 16384 + c * 128 + i] = u;
}

// ---- fused epilogue+makeB: 256 blocks x 32 rows.
//      FIRST=1: A-rows from concat(pos,emb)*isd; FIRST=0: reduce 4 partials + softplus.
//      Then Bt[c][k] = (A @ W)^T for this 32-row tile. ----
template<int FIRST>
__global__ __launch_bounds__(256) void k_emb(const void* __restrict__ pos,
                                             const void* __restrict__ emb,
                                             const float* __restrict__ partial,
                                             const float* __restrict__ isd,
                                             const void* __restrict__ bsv,
                                             int lyr, const int* __restrict__ flagp,
                                             const unsigned short* __restrict__ Wt,
                                             unsigned short* __restrict__ Bt){
  __shared__ char lds[40960];                 // A [0,8K), Wt [8K,40K); bounce reuses [0,10.2K)
  const int t = threadIdx.x, wid = t >> 6, l = t & 63;
  const int r0 = blockIdx.x * 32;
  const int mode = *flagp;

  // phase 1: build A-rows (16 cols per thread), write swizzled bf16 A-tile
  {
    const int r = t >> 3, c0 = (t & 7) * 16;
    const float sc = isd[r0 + r];
    float v[16];
    if(FIRST){
      #pragma unroll
      for(int j = 0; j < 16; ++j){
        int c = c0 + j;
        float x;
        if(mode) x = b2f(c < 3 ? ((const unsigned short*)pos)[(r0 + r) * 3 + c]
                               : ((const unsigned short*)emb)[(r0 + r) * 125 + (c - 3)]);
        else     x = (c < 3) ? ((const float*)pos)[(r0 + r) * 3 + c]
                             : ((const float*)emb)[(r0 + r) * 125 + (c - 3)];
        v[j] = x * sc;
      }
    } else {
      float s[16];
      #pragma unroll
      for(int j = 0; j < 16; ++j) s[j] = 0.f;
      #pragma unroll
      for(int p = 0; p < 4; ++p){
        const float* pp = partial + ((size_t)p << 20) + (size_t)(r0 + r) * HID + c0;
        #pragma unroll
        for(int g = 0; g < 4; ++g){
          f32x4 a = *(const f32x4*)(pp + g * 4);
          s[g*4+0] += a[0]; s[g*4+1] += a[1]; s[g*4+2] += a[2]; s[g*4+3] += a[3];
        }
      }
      #pragma unroll
      for(int j = 0; j < 16; ++j){
        float b = mode ? b2f(((const unsigned short*)bsv)[(lyr - 1) * 128 + c0 + j])
                       : ((const float*)bsv)[(lyr - 1) * 128 + c0 + j];
        float h = s[j] * sc + b;
        float sp = fmaxf(h, 0.f) + log1pf(expf(-fabsf(h)));   // stable softplus
        v[j] = sp * sc;                                        // pre-scale for next layer
      }
    }
    u16x8 w0, w1;
    #pragma unroll
    for(int j = 0; j < 8; ++j){ w0[j] = f2b(v[j]); w1[j] = f2b(v[8 + j]); }
    *(u16x8*)(lds + r * 256 + ((c0 * 2)      ^ ((r & 7) << 4))) = w0;
    *(u16x8*)(lds + r * 256 + ((c0 * 2 + 16) ^ ((r & 7) << 4))) = w1;
  }
  // phase 2: stage Wt (128 x 256B) into lds+8192, pre-swizzled source
  {
    const char* Wl = (const char*)(Wt + lyr * 16384);
    #pragma unroll
    for(int q = 0; q < 8; ++q){
      int ob = q * 4096 + wid * 1024;
      int o  = ob + l * 16;
      int c  = o >> 8, x = o & 255;
      gld_lds16(Wl + c * 256 + (x ^ ((c & 7) << 4)), lds + 8192 + ob);
    }
  }
  __syncthreads();
  // phase 3: MFMA — wave w covers B-cols [w*32, w*32+32)
  const int rlo = l & 31;
  f32x16 acc;
  #pragma unroll
  for(int r2 = 0; r2 < 16; ++r2) acc[r2] = 0.f;
  {
    const int swz = (l & 7) << 4;
    #pragma unroll
    for(int s = 0; s < 8; ++s){
      int ko = (s * 32 + ((l >> 5) << 4)) ^ swz;
      bf16x8 a = *(const bf16x8*)(lds + rlo * 256 + ko);
      bf16x8 b = *(const bf16x8*)(lds + 8192 + (wid * 32 + rlo) * 256 + ko);
      acc = __builtin_amdgcn_mfma_f32_32x32x16_bf16(a, b, acc, 0, 0, 0);
    }
  }
  __syncthreads();
  // phase 4: bounce transpose [128 c][40 r] u16 (80B rows)
  {
    int c = wid * 32 + rlo;
    #pragma unroll
    for(int reg = 0; reg < 16; ++reg){
      int r = (reg & 3) + 8 * (reg >> 2) + 4 * (l >> 5);
      *(unsigned short*)(lds + c * 80 + r * 2) = f2b(acc[reg]);
    }
  }
  __syncthreads();
  // phase 5: write Bt: 128 c x 32 r = 512 chunks of 16B
  #pragma unroll
  for(int q = 0; q < 2; ++q){
    int id = q * 256 + t;
    int c = id >> 2, xc = id & 3;
    u16x8 v = *(const u16x8*)(lds + c * 80 + xc * 16);
    *(u16x8*)((char*)Bt + (size_t)c * (NN * 2) + (size_t)r0 * 2 + xc * 16) = v;
  }
}

// ------ main GEMM: BM=128, BN=128, BK=32, 8 waves (32x64 wave tile), KSPLIT=4
//        5-buffer distance-4 pipeline, vmcnt(6) steady state, setprio on MFMA ------
__global__ __launch_bounds__(512) void k_gemm(const void* __restrict__ adj_in,
                                              const unsigned short* __restrict__ adjb,
                                              const unsigned short* __restrict__ Bt,
                                              const int* __restrict__ flagp,
                                              float* __restrict__ partial){
  __shared__ char lds[81920];                 // 5 bufs x (A 8KiB + B 8KiB), 64B rows
  const int t = threadIdx.x, wid = t >> 6, l = t & 63;
  const int r0 = blockIdx.x * 128;
  const int kbase = blockIdx.y * 2048;
  const unsigned short* A = (*flagp) ? (const unsigned short*)adj_in : adjb;

  // 2 gld_lds16 instructions per wave per stage
  auto stage = [&](int buf, int kt){
    const int bb = buf * 16384;
    {                                         // A: 128 rows x 64B
      int ob = wid * 1024;
      int o = ob + l * 16;
      int row = o >> 6, x = o & 63;
      gld_lds16((const char*)A + ((size_t)(r0 + row) * NN + kt) * 2
                + (x ^ (((row >> 1) & 3) << 4)), lds + bb + ob);
    }
    {                                         // B: 128 cols x 64B
      int ob = wid * 1024;
      int o = ob + l * 16;
      int c = o >> 6, x = o & 63;
      gld_lds16((const char*)Bt + ((size_t)c * NN + kt) * 2
                + (x ^ (((c >> 1) & 3) << 4)), lds + bb + 8192 + ob);
    }
  };

  const int wr = wid >> 1, wc = wid & 1;      // wave tile: 32 rows x 64 cols
  f32x16 acc[2];
  #pragma unroll
  for(int b = 0; b < 2; ++b)
    #pragma unroll
    for(int r2 = 0; r2 < 16; ++r2) acc[b][r2] = 0.f;

  const int rlo = l & 31;
  const int swz = ((l >> 1) & 3) << 4;
  const int khalf = (l >> 5) << 4;

  auto compute = [&](int buf){
    const int bb = buf * 16384;
    __builtin_amdgcn_s_setprio(1);            // T5: favor MFMA-entering waves
    #pragma unroll
    for(int kk = 0; kk < 2; ++kk){
      int ko = (kk * 32 + khalf) ^ swz;
      bf16x8 a  = *(const bf16x8*)(lds + bb +        (wr * 32 + rlo)      * 64 + ko);
      bf16x8 b0 = *(const bf16x8*)(lds + bb + 8192 + (wc * 64 + rlo)      * 64 + ko);
      bf16x8 b1 = *(const bf16x8*)(lds + bb + 8192 + (wc * 64 + rlo + 32) * 64 + ko);
      acc[0] = __builtin_amdgcn_mfma_f32_32x32x16_bf16(a, b0, acc[0], 0, 0, 0);
      acc[1] = __builtin_amdgcn_mfma_f32_32x32x16_bf16(a, b1, acc[1], 0, 0, 0);
    }
    __builtin_amdgcn_s_setprio(0);
  };

  stage(0, kbase);
  stage(1, kbase + 32);
  stage(2, kbase + 64);
  stage(3, kbase + 96);
  int bc = 0, bs = 4;                          // ring counters (avoid runtime %)
  for(int it = 0; it < 60; ++it){
    asm volatile("s_waitcnt vmcnt(6)" ::: "memory");   // drain own stage-it (3 stages in flight)
    __builtin_amdgcn_s_barrier();
    __builtin_amdgcn_sched_barrier(0);
    stage(bs, kbase + (it + 4) * 32);          // WAR-safe: its readers passed this barrier
    compute(bc);
    bc = (bc == 4) ? 0 : bc + 1;
    bs = (bs == 4) ? 0 : bs + 1;
  }
  asm volatile("s_waitcnt vmcnt(6)" ::: "memory");     // it=60: 8 outstanding -> drains st60
  __builtin_amdgcn_s_barrier();
  __builtin_amdgcn_sched_barrier(0);
  compute(0);
  asm volatile("s_waitcnt vmcnt(4)" ::: "memory");
  __builtin_amdgcn_s_barrier();
  __builtin_amdgcn_sched_barrier(0);
  compute(1);
  asm volatile("s_waitcnt vmcnt(2)" ::: "memory");
  __builtin_amdgcn_s_barrier();
  __builtin_amdgcn_sched_barrier(0);
  compute(2);
  asm volatile("s_waitcnt vmcnt(0)" ::: "memory");
  __builtin_amdgcn_s_barrier();
  __builtin_amdgcn_sched_barrier(0);
  compute(3);

  float* pp = partial + ((size_t)blockIdx.y << 20);
  #pragma unroll
  for(int ni = 0; ni < 2; ++ni)
    #pragma unroll
    for(int reg = 0; reg < 16; ++reg){
      int r = r0 + wr * 32 + (reg & 3) + 8 * (reg >> 2) + 4 * (l >> 5);
      int c = wc * 64 + ni * 32 + rlo;
      pp[(size_t)r * HID + c] = acc[ni][reg];
    }
}

// ------ final epilogue: reduce 4 partials + norm + bias + softplus -> out ------
__global__ __launch_bounds__(256) void k_out(const float* __restrict__ partial,
                                             const float* __restrict__ isd,
                                             const void* __restrict__ bsv,
                                             const int* __restrict__ flagp,
                                             void* __restrict__ out){
  const int x = blockIdx.x * 256 + threadIdx.x;
  float v = 0.f;
  #pragma unroll
  for(int p = 0; p < 4; ++p) v += partial[((size_t)p << 20) + x];
  const int r = x >> 7, c = x & 127;
  const int mode = *flagp;
  float b = mode ? b2f(((const unsigned short*)bsv)[3 * 128 + c])
                 : ((const float*)bsv)[3 * 128 + c];
  v = v * isd[r] + b;
  float sp = fmaxf(v, 0.f) + log1pf(expf(-fabsf(v)));
  if(mode) ((unsigned short*)out)[x] = f2b(sp);
  else     ((float*)out)[x] = sp;
}

extern "C" void kernel_launch(void* const* d_in, const int* in_sizes, int n_in,
                              void* d_out, int out_size, void* d_ws, size_t ws_size,
                              hipStream_t stream){
  const void* pos = d_in[0];
  const void* emb = d_in[1];
  const void* adj = d_in[2];
  const void* Ws  = d_in[3];
  const void* bs  = d_in[4];

  // ws: flag@0 | isd@0x1000 | Bt@0x210000 (2M) | Wt@0x410000 (128K)
  //     partial@0x430000 (16M) | adjb@0x2430000 (128M)
  char* ws = (char*)d_ws;
  int*            flag    = (int*)(ws);
  float*          isd     = (float*)(ws + 0x1000);
  unsigned short* Bt      = (unsigned short*)(ws + 0x210000);
  unsigned short* Wt      = (unsigned short*)(ws + 0x410000);
  float*          partial = (float*)(ws + 0x430000);
  unsigned short* adjb    = (unsigned short*)(ws + 0x2430000);

  k_detect<<<1,    256, 0, stream>>>((const unsigned int*)adj, flag);
  k_degcvt<<<2048, 256, 0, stream>>>(adj, flag, isd, adjb);
  k_wt    <<<256,  256, 0, stream>>>(Ws, flag, Wt);

  for(int lyr = 0; lyr < 4; ++lyr){
    if(lyr == 0) k_emb<1><<<256, 256, 0, stream>>>(pos, emb, partial, isd, bs, 0,   flag, Wt, Bt);
    else         k_emb<0><<<256, 256, 0, stream>>>(pos, emb, partial, isd, bs, lyr, flag, Wt, Bt);
    k_gemm<<<dim3(64, 4), 512, 0, stream>>>(adj, adjb, Bt, flag, partial);
  }
  k_out<<<4096, 256, 0, stream>>>(partial, isd, bs, flag, d_out);
}

// Round 13
// 242.099 us; speedup vs baseline: 1.0062x; 1.0062x over previous
//
#include <hip/hip_runtime.h>
#include <hip/hip_bf16.h>
#include <cstdint>

#define NN   8192
#define HID  128

typedef __attribute__((ext_vector_type(8)))  __bf16          bf16x8;
typedef __attribute__((ext_vector_type(16))) float           f32x16;
typedef __attribute__((ext_vector_type(8)))  unsigned short  u16x8;
typedef __attribute__((ext_vector_type(4)))  unsigned short  u16x4;
typedef __attribute__((ext_vector_type(4)))  float           f32x4;

__device__ __forceinline__ float b2f(unsigned short u){
  union { unsigned int i; float f; } v; v.i = ((unsigned int)u) << 16; return v.f;
}
__device__ __forceinline__ unsigned short f2b(float f){
  unsigned int i = __float_as_uint(f);
  unsigned int r = (i + 0x7FFFu + ((i >> 16) & 1u)) >> 16;   // RNE
  return (unsigned short)r;
}
__device__ __forceinline__ void gld_lds16(const void* g, void* l){
  __builtin_amdgcn_global_load_lds((const __attribute__((address_space(1))) unsigned int*)g,
                                   (__attribute__((address_space(3))) unsigned int*)l, 16, 0, 0);
}

// ---------------- dtype detect: bf16 buffers -> flag=1, f32 -> flag=0 ----------------
__global__ __launch_bounds__(256) void k_detect(const unsigned int* __restrict__ a,
                                                int* __restrict__ flag){
  __shared__ int cnt;
  if(threadIdx.x == 0) cnt = 0;
  __syncthreads();
  int c = 0;
  #pragma unroll
  for(int i = 0; i < 16; ++i){
    unsigned int w = a[i * 256 + threadIdx.x];
    c += (((w >> 8) & 0xC0u) == 0u) ? 1 : 0;
  }
  atomicAdd(&cnt, c);
  __syncthreads();
  if(threadIdx.x == 0) *flag = (cnt > 3000) ? 1 : 0;
}

// -------- deg + inv_sqrt_deg, fused f32->bf16 adj convert (one wave per row) --------
__global__ __launch_bounds__(256) void k_degcvt(const void* __restrict__ adjv,
                                                const int* __restrict__ flagp,
                                                float* __restrict__ isd,
                                                unsigned short* __restrict__ adjb){
  const int wid = threadIdx.x >> 6, l = threadIdx.x & 63;
  const int row = blockIdx.x * 4 + wid;
  float s = 0.f;
  if(*flagp){
    const u16x8* rp = (const u16x8*)((const unsigned short*)adjv + (size_t)row * NN);
    #pragma unroll
    for(int it = 0; it < 16; ++it){
      u16x8 v = rp[it * 64 + l];
      #pragma unroll
      for(int j = 0; j < 8; ++j) s += b2f(v[j]);
    }
  } else {
    const f32x4* rp = (const f32x4*)((const float*)adjv + (size_t)row * NN);
    u16x4* wp = (u16x4*)(adjb + (size_t)row * NN);
    #pragma unroll
    for(int it = 0; it < 32; ++it){
      f32x4 v = rp[it * 64 + l];
      s += v[0] + v[1] + v[2] + v[3];
      u16x4 w;
      w[0] = f2b(v[0]); w[1] = f2b(v[1]); w[2] = f2b(v[2]); w[3] = f2b(v[3]);
      wp[it * 64 + l] = w;
    }
  }
  #pragma unroll
  for(int m = 32; m > 0; m >>= 1) s += __shfl_xor(s, m, 64);
  if(l == 0) isd[row] = (s > 0.f) ? rsqrtf(fmaxf(s, 1e-12f)) : 0.f;
}

// ---------------- W transpose to bf16: Wt[l][c][i] = bf16(Ws[l][i][c]) ----------------
__global__ __launch_bounds__(256) void k_wt(const void* __restrict__ Ws,
                                            const int* __restrict__ flagp,
                                            unsigned short* __restrict__ Wt){
  const int x = blockIdx.x * 256 + threadIdx.x;
  const int lyr = x >> 14, rem = x & 16383, i = rem >> 7, c = rem & 127;
  unsigned short u;
  if(*flagp) u = ((const unsigned short*)Ws)[x];
  else       u = f2b(((const float*)Ws)[x]);
  Wt[lyr * 16384 + c * 128 + i] = u;
}

// ---- fused epilogue+makeB: 256 blocks x 32 rows.
//      FIRST=1: A-rows from concat(pos,emb)*isd; FIRST=0: reduce 8 partials + softplus.
//      Then Bt[c][k] = (A @ W)^T for this 32-row tile. ----
template<int FIRST>
__global__ __launch_bounds__(256) void k_emb(const void* __restrict__ pos,
                                             const void* __restrict__ emb,
                                             const float* __restrict__ partial,
                                             const float* __restrict__ isd,
                                             const void* __restrict__ bsv,
                                             int lyr, const int* __restrict__ flagp,
                                             const unsigned short* __restrict__ Wt,
                                             unsigned short* __restrict__ Bt){
  __shared__ char lds[40960];                 // A [0,8K), Wt [8K,40K); bounce reuses [0,10.2K)
  const int t = threadIdx.x, wid = t >> 6, l = t & 63;
  const int r0 = blockIdx.x * 32;
  const int mode = *flagp;

  // phase 1: build A-rows (16 cols per thread), write swizzled bf16 A-tile
  {
    const int r = t >> 3, c0 = (t & 7) * 16;
    const float sc = isd[r0 + r];
    float v[16];
    if(FIRST){
      #pragma unroll
      for(int j = 0; j < 16; ++j){
        int c = c0 + j;
        float x;
        if(mode) x = b2f(c < 3 ? ((const unsigned short*)pos)[(r0 + r) * 3 + c]
                               : ((const unsigned short*)emb)[(r0 + r) * 125 + (c - 3)]);
        else     x = (c < 3) ? ((const float*)pos)[(r0 + r) * 3 + c]
                             : ((const float*)emb)[(r0 + r) * 125 + (c - 3)];
        v[j] = x * sc;
      }
    } else {
      float s[16];
      #pragma unroll
      for(int j = 0; j < 16; ++j) s[j] = 0.f;
      #pragma unroll
      for(int p = 0; p < 8; ++p){
        const float* pp = partial + ((size_t)p << 20) + (size_t)(r0 + r) * HID + c0;
        #pragma unroll
        for(int g = 0; g < 4; ++g){
          f32x4 a = *(const f32x4*)(pp + g * 4);
          s[g*4+0] += a[0]; s[g*4+1] += a[1]; s[g*4+2] += a[2]; s[g*4+3] += a[3];
        }
      }
      #pragma unroll
      for(int j = 0; j < 16; ++j){
        float b = mode ? b2f(((const unsigned short*)bsv)[(lyr - 1) * 128 + c0 + j])
                       : ((const float*)bsv)[(lyr - 1) * 128 + c0 + j];
        float h = s[j] * sc + b;
        float sp = fmaxf(h, 0.f) + log1pf(expf(-fabsf(h)));   // stable softplus
        v[j] = sp * sc;                                        // pre-scale for next layer
      }
    }
    u16x8 w0, w1;
    #pragma unroll
    for(int j = 0; j < 8; ++j){ w0[j] = f2b(v[j]); w1[j] = f2b(v[8 + j]); }
    *(u16x8*)(lds + r * 256 + ((c0 * 2)      ^ ((r & 7) << 4))) = w0;
    *(u16x8*)(lds + r * 256 + ((c0 * 2 + 16) ^ ((r & 7) << 4))) = w1;
  }
  // phase 2: stage Wt (128 x 256B) into lds+8192, pre-swizzled source
  {
    const char* Wl = (const char*)(Wt + lyr * 16384);
    #pragma unroll
    for(int q = 0; q < 8; ++q){
      int ob = q * 4096 + wid * 1024;
      int o  = ob + l * 16;
      int c  = o >> 8, x = o & 255;
      gld_lds16(Wl + c * 256 + (x ^ ((c & 7) << 4)), lds + 8192 + ob);
    }
  }
  __syncthreads();
  // phase 3: MFMA — wave w covers B-cols [w*32, w*32+32)
  const int rlo = l & 31;
  f32x16 acc;
  #pragma unroll
  for(int r2 = 0; r2 < 16; ++r2) acc[r2] = 0.f;
  {
    const int swz = (l & 7) << 4;
    #pragma unroll
    for(int s = 0; s < 8; ++s){
      int ko = (s * 32 + ((l >> 5) << 4)) ^ swz;
      bf16x8 a = *(const bf16x8*)(lds + rlo * 256 + ko);
      bf16x8 b = *(const bf16x8*)(lds + 8192 + (wid * 32 + rlo) * 256 + ko);
      acc = __builtin_amdgcn_mfma_f32_32x32x16_bf16(a, b, acc, 0, 0, 0);
    }
  }
  __syncthreads();
  // phase 4: bounce transpose [128 c][40 r] u16 (80B rows)
  {
    int c = wid * 32 + rlo;
    #pragma unroll
    for(int reg = 0; reg < 16; ++reg){
      int r = (reg & 3) + 8 * (reg >> 2) + 4 * (l >> 5);
      *(unsigned short*)(lds + c * 80 + r * 2) = f2b(acc[reg]);
    }
  }
  __syncthreads();
  // phase 5: write Bt: 128 c x 32 r = 512 chunks of 16B
  #pragma unroll
  for(int q = 0; q < 2; ++q){
    int id = q * 256 + t;
    int c = id >> 2, xc = id & 3;
    u16x8 v = *(const u16x8*)(lds + c * 80 + xc * 16);
    *(u16x8*)((char*)Bt + (size_t)c * (NN * 2) + (size_t)r0 * 2 + xc * 16) = v;
  }
}

// ------ main GEMM: BM=256, BN=128, BK=64, 8 waves (64x64 wave tile), KSPLIT=8
//        ring-3 distance-2 pipeline, vmcnt(6) steady state, 16 iters/window ------
__global__ __launch_bounds__(512) void k_gemm(const void* __restrict__ adj_in,
                                              const unsigned short* __restrict__ adjb,
                                              const unsigned short* __restrict__ Bt,
                                              const int* __restrict__ flagp,
                                              float* __restrict__ partial){
  __shared__ char lds[147456];                // 3 bufs x (A 32KiB + B 16KiB), 128B rows
  const int t = threadIdx.x, wid = t >> 6, l = t & 63;
  const int r0 = blockIdx.x * 256;
  const int kbase = blockIdx.y * 1024;
  const unsigned short* A = (*flagp) ? (const unsigned short*)adj_in : adjb;

  // 6 gld_lds16 per wave per stage (A 4 + B 2), 128-B rows, (row&7)<<4 swizzle
  auto stage = [&](int buf, int kt){
    const int bb = buf * 49152;
    #pragma unroll
    for(int q = 0; q < 4; ++q){               // A: 256 rows x 128B
      int ob = q * 8192 + wid * 1024;
      int o = ob + l * 16;
      int row = o >> 7, x = o & 127;
      gld_lds16((const char*)A + ((size_t)(r0 + row) * NN + kt) * 2
                + (x ^ ((row & 7) << 4)), lds + bb + ob);
    }
    #pragma unroll
    for(int q = 0; q < 2; ++q){               // B: 128 cols x 128B
      int ob = q * 8192 + wid * 1024;
      int o = ob + l * 16;
      int c = o >> 7, x = o & 127;
      gld_lds16((const char*)Bt + ((size_t)c * NN + kt) * 2
                + (x ^ ((c & 7) << 4)), lds + bb + 32768 + ob);
    }
  };

  const int wr = wid >> 1, wc = wid & 1;      // wave tile: 64 rows x 64 cols
  f32x16 acc[2][2];
  #pragma unroll
  for(int a = 0; a < 2; ++a)
    #pragma unroll
    for(int b = 0; b < 2; ++b)
      #pragma unroll
      for(int r2 = 0; r2 < 16; ++r2) acc[a][b][r2] = 0.f;

  const int rlo = l & 31;
  const int swz = (l & 7) << 4;
  const int khalf = (l >> 5) << 4;

  auto compute = [&](int buf){
    const int bb = buf * 49152;
    #pragma unroll
    for(int kk = 0; kk < 4; ++kk){
      int ko = (kk * 32 + khalf) ^ swz;
      bf16x8 a0 = *(const bf16x8*)(lds + bb +         (wr * 64 + rlo)      * 128 + ko);
      bf16x8 a1 = *(const bf16x8*)(lds + bb +         (wr * 64 + rlo + 32) * 128 + ko);
      bf16x8 b0 = *(const bf16x8*)(lds + bb + 32768 + (wc * 64 + rlo)      * 128 + ko);
      bf16x8 b1 = *(const bf16x8*)(lds + bb + 32768 + (wc * 64 + rlo + 32) * 128 + ko);
      acc[0][0] = __builtin_amdgcn_mfma_f32_32x32x16_bf16(a0, b0, acc[0][0], 0, 0, 0);
      acc[0][1] = __builtin_amdgcn_mfma_f32_32x32x16_bf16(a0, b1, acc[0][1], 0, 0, 0);
      acc[1][0] = __builtin_amdgcn_mfma_f32_32x32x16_bf16(a1, b0, acc[1][0], 0, 0, 0);
      acc[1][1] = __builtin_amdgcn_mfma_f32_32x32x16_bf16(a1, b1, acc[1][1], 0, 0, 0);
    }
  };

  stage(0, kbase);
  stage(1, kbase + 64);
  int bc = 0, bs = 2;                          // ring counters
  for(int it = 0; it < 14; ++it){
    asm volatile("s_waitcnt vmcnt(6)" ::: "memory");   // drain own stage-it (1 stage in flight)
    __builtin_amdgcn_s_barrier();
    __builtin_amdgcn_sched_barrier(0);
    stage(bs, kbase + (it + 2) * 64);          // WAR-safe: its readers passed this barrier
    compute(bc);
    bc = (bc == 2) ? 0 : bc + 1;
    bs = (bs == 2) ? 0 : bs + 1;
  }
  asm volatile("s_waitcnt vmcnt(6)" ::: "memory");     // drains stage 14
  __builtin_amdgcn_s_barrier();
  __builtin_amdgcn_sched_barrier(0);
  compute(2);                                  // it=14: buf 14%3=2
  asm volatile("s_waitcnt vmcnt(0)" ::: "memory");
  __builtin_amdgcn_s_barrier();
  __builtin_amdgcn_sched_barrier(0);
  compute(0);                                  // it=15: buf 15%3=0

  float* pp = partial + ((size_t)blockIdx.y << 20);
  #pragma unroll
  for(int mi = 0; mi < 2; ++mi)
    #pragma unroll
    for(int ni = 0; ni < 2; ++ni)
      #pragma unroll
      for(int reg = 0; reg < 16; ++reg){
        int r = r0 + wr * 64 + mi * 32 + (reg & 3) + 8 * (reg >> 2) + 4 * (l >> 5);
        int c = wc * 64 + ni * 32 + rlo;
        pp[(size_t)r * HID + c] = acc[mi][ni][reg];
      }
}

// ------ final epilogue: reduce 8 partials + norm + bias + softplus -> out ------
__global__ __launch_bounds__(256) void k_out(const float* __restrict__ partial,
                                             const float* __restrict__ isd,
                                             const void* __restrict__ bsv,
                                             const int* __restrict__ flagp,
                                             void* __restrict__ out){
  const int x = blockIdx.x * 256 + threadIdx.x;
  float v = 0.f;
  #pragma unroll
  for(int p = 0; p < 8; ++p) v += partial[((size_t)p << 20) + x];
  const int r = x >> 7, c = x & 127;
  const int mode = *flagp;
  float b = mode ? b2f(((const unsigned short*)bsv)[3 * 128 + c])
                 : ((const float*)bsv)[3 * 128 + c];
  v = v * isd[r] + b;
  float sp = fmaxf(v, 0.f) + log1pf(expf(-fabsf(v)));
  if(mode) ((unsigned short*)out)[x] = f2b(sp);
  else     ((float*)out)[x] = sp;
}

extern "C" void kernel_launch(void* const* d_in, const int* in_sizes, int n_in,
                              void* d_out, int out_size, void* d_ws, size_t ws_size,
                              hipStream_t stream){
  const void* pos = d_in[0];
  const void* emb = d_in[1];
  const void* adj = d_in[2];
  const void* Ws  = d_in[3];
  const void* bs  = d_in[4];

  // ws: flag@0 | isd@0x1000 | Bt@0x210000 (2M) | Wt@0x410000 (128K)
  //     partial@0x430000 (32M) | adjb@0x2430000 (128M)
  char* ws = (char*)d_ws;
  int*            flag    = (int*)(ws);
  float*          isd     = (float*)(ws + 0x1000);
  unsigned short* Bt      = (unsigned short*)(ws + 0x210000);
  unsigned short* Wt      = (unsigned short*)(ws + 0x410000);
  float*          partial = (float*)(ws + 0x430000);
  unsigned short* adjb    = (unsigned short*)(ws + 0x2430000);

  k_detect<<<1,    256, 0, stream>>>((const unsigned int*)adj, flag);
  k_degcvt<<<2048, 256, 0, stream>>>(adj, flag, isd, adjb);
  k_wt    <<<256,  256, 0, stream>>>(Ws, flag, Wt);

  for(int lyr = 0; lyr < 4; ++lyr){
    if(lyr == 0) k_emb<1><<<256, 256, 0, stream>>>(pos, emb, partial, isd, bs, 0,   flag, Wt, Bt);
    else         k_emb<0><<<256, 256, 0, stream>>>(pos, emb, partial, isd, bs, lyr, flag, Wt, Bt);
    k_gemm<<<dim3(32, 8), 512, 0, stream>>>(adj, adjb, Bt, flag, partial);
  }
  k_out<<<4096, 256, 0, stream>>>(partial, isd, bs, flag, d_out);
}

// Round 14
// 228.672 us; speedup vs baseline: 1.0653x; 1.0587x over previous
//
#include <hip/hip_runtime.h>
#include <hip/hip_bf16.h>
#include <cstdint>

#define NN   8192
#define HID  128

typedef __attribute__((ext_vector_type(8)))  __bf16          bf16x8;
typedef __attribute__((ext_vector_type(16))) float           f32x16;
typedef __attribute__((ext_vector_type(8)))  unsigned short  u16x8;
typedef __attribute__((ext_vector_type(4)))  unsigned short  u16x4;
typedef __attribute__((ext_vector_type(4)))  float           f32x4;

__device__ __forceinline__ float b2f(unsigned short u){
  union { unsigned int i; float f; } v; v.i = ((unsigned int)u) << 16; return v.f;
}
__device__ __forceinline__ unsigned short f2b(float f){
  unsigned int i = __float_as_uint(f);
  unsigned int r = (i + 0x7FFFu + ((i >> 16) & 1u)) >> 16;   // RNE
  return (unsigned short)r;
}
__device__ __forceinline__ void gld_lds16(const void* g, void* l){
  __builtin_amdgcn_global_load_lds((const __attribute__((address_space(1))) unsigned int*)g,
                                   (__attribute__((address_space(3))) unsigned int*)l, 16, 0, 0);
}

// ---------------- dtype detect: bf16 buffers -> flag=1, f32 -> flag=0 ----------------
__global__ __launch_bounds__(256) void k_detect(const unsigned int* __restrict__ a,
                                                int* __restrict__ flag){
  __shared__ int cnt;
  if(threadIdx.x == 0) cnt = 0;
  __syncthreads();
  int c = 0;
  #pragma unroll
  for(int i = 0; i < 16; ++i){
    unsigned int w = a[i * 256 + threadIdx.x];
    c += (((w >> 8) & 0xC0u) == 0u) ? 1 : 0;
  }
  atomicAdd(&cnt, c);
  __syncthreads();
  if(threadIdx.x == 0) *flag = (cnt > 3000) ? 1 : 0;
}

// -------- deg + inv_sqrt_deg, fused f32->bf16 adj convert (one wave per row) --------
__global__ __launch_bounds__(256) void k_degcvt(const void* __restrict__ adjv,
                                                const int* __restrict__ flagp,
                                                float* __restrict__ isd,
                                                unsigned short* __restrict__ adjb){
  const int wid = threadIdx.x >> 6, l = threadIdx.x & 63;
  const int row = blockIdx.x * 4 + wid;
  float s = 0.f;
  if(*flagp){
    const u16x8* rp = (const u16x8*)((const unsigned short*)adjv + (size_t)row * NN);
    #pragma unroll
    for(int it = 0; it < 16; ++it){
      u16x8 v = rp[it * 64 + l];
      #pragma unroll
      for(int j = 0; j < 8; ++j) s += b2f(v[j]);
    }
  } else {
    const f32x4* rp = (const f32x4*)((const float*)adjv + (size_t)row * NN);
    u16x4* wp = (u16x4*)(adjb + (size_t)row * NN);
    #pragma unroll
    for(int it = 0; it < 32; ++it){
      f32x4 v = rp[it * 64 + l];
      s += v[0] + v[1] + v[2] + v[3];
      u16x4 w;
      w[0] = f2b(v[0]); w[1] = f2b(v[1]); w[2] = f2b(v[2]); w[3] = f2b(v[3]);
      wp[it * 64 + l] = w;
    }
  }
  #pragma unroll
  for(int m = 32; m > 0; m >>= 1) s += __shfl_xor(s, m, 64);
  if(l == 0) isd[row] = (s > 0.f) ? rsqrtf(fmaxf(s, 1e-12f)) : 0.f;
}

// ---------------- W transpose to bf16: Wt[l][c][i] = bf16(Ws[l][i][c]) ----------------
__global__ __launch_bounds__(256) void k_wt(const void* __restrict__ Ws,
                                            const int* __restrict__ flagp,
                                            unsigned short* __restrict__ Wt){
  const int x = blockIdx.x * 256 + threadIdx.x;
  const int lyr = x >> 14, rem = x & 16383, i = rem >> 7, c = rem & 127;
  unsigned short u;
  if(*flagp) u = ((const unsigned short*)Ws)[x];
  else       u = f2b(((const float*)Ws)[x]);
  Wt[lyr * 16384 + c * 128 + i] = u;
}

// ---- fused epilogue+makeB: 256 blocks x 32 rows. partials are bf16 now. ----
template<int FIRST>
__global__ __launch_bounds__(256) void k_emb(const void* __restrict__ pos,
                                             const void* __restrict__ emb,
                                             const unsigned short* __restrict__ partial,
                                             const float* __restrict__ isd,
                                             const void* __restrict__ bsv,
                                             int lyr, const int* __restrict__ flagp,
                                             const unsigned short* __restrict__ Wt,
                                             unsigned short* __restrict__ Bt){
  __shared__ char lds[40960];                 // A [0,8K), Wt [8K,40K); bounce reuses [0,10.2K)
  const int t = threadIdx.x, wid = t >> 6, l = t & 63;
  const int r0 = blockIdx.x * 32;
  const int mode = *flagp;

  // phase 1: build A-rows (16 cols per thread), write swizzled bf16 A-tile
  {
    const int r = t >> 3, c0 = (t & 7) * 16;
    const float sc = isd[r0 + r];
    float v[16];
    if(FIRST){
      #pragma unroll
      for(int j = 0; j < 16; ++j){
        int c = c0 + j;
        float x;
        if(mode) x = b2f(c < 3 ? ((const unsigned short*)pos)[(r0 + r) * 3 + c]
                               : ((const unsigned short*)emb)[(r0 + r) * 125 + (c - 3)]);
        else     x = (c < 3) ? ((const float*)pos)[(r0 + r) * 3 + c]
                             : ((const float*)emb)[(r0 + r) * 125 + (c - 3)];
        v[j] = x * sc;
      }
    } else {
      float s[16];
      #pragma unroll
      for(int j = 0; j < 16; ++j) s[j] = 0.f;
      #pragma unroll
      for(int p = 0; p < 8; ++p){
        const unsigned short* pp = partial + ((size_t)p << 20) + (size_t)(r0 + r) * HID + c0;
        u16x8 a0 = *(const u16x8*)pp;
        u16x8 a1 = *(const u16x8*)(pp + 8);
        #pragma unroll
        for(int j = 0; j < 8; ++j){ s[j] += b2f(a0[j]); s[8 + j] += b2f(a1[j]); }
      }
      #pragma unroll
      for(int j = 0; j < 16; ++j){
        float b = mode ? b2f(((const unsigned short*)bsv)[(lyr - 1) * 128 + c0 + j])
                       : ((const float*)bsv)[(lyr - 1) * 128 + c0 + j];
        float h = s[j] * sc + b;
        float sp = fmaxf(h, 0.f) + log1pf(expf(-fabsf(h)));   // stable softplus
        v[j] = sp * sc;                                        // pre-scale for next layer
      }
    }
    u16x8 w0, w1;
    #pragma unroll
    for(int j = 0; j < 8; ++j){ w0[j] = f2b(v[j]); w1[j] = f2b(v[8 + j]); }
    *(u16x8*)(lds + r * 256 + ((c0 * 2)      ^ ((r & 7) << 4))) = w0;
    *(u16x8*)(lds + r * 256 + ((c0 * 2 + 16) ^ ((r & 7) << 4))) = w1;
  }
  // phase 2: stage Wt (128 x 256B) into lds+8192, pre-swizzled source
  {
    const char* Wl = (const char*)(Wt + lyr * 16384);
    #pragma unroll
    for(int q = 0; q < 8; ++q){
      int ob = q * 4096 + wid * 1024;
      int o  = ob + l * 16;
      int c  = o >> 8, x = o & 255;
      gld_lds16(Wl + c * 256 + (x ^ ((c & 7) << 4)), lds + 8192 + ob);
    }
  }
  __syncthreads();
  // phase 3: MFMA — wave w covers B-cols [w*32, w*32+32)
  const int rlo = l & 31;
  f32x16 acc;
  #pragma unroll
  for(int r2 = 0; r2 < 16; ++r2) acc[r2] = 0.f;
  {
    const int swz = (l & 7) << 4;
    #pragma unroll
    for(int s = 0; s < 8; ++s){
      int ko = (s * 32 + ((l >> 5) << 4)) ^ swz;
      bf16x8 a = *(const bf16x8*)(lds + rlo * 256 + ko);
      bf16x8 b = *(const bf16x8*)(lds + 8192 + (wid * 32 + rlo) * 256 + ko);
      acc = __builtin_amdgcn_mfma_f32_32x32x16_bf16(a, b, acc, 0, 0, 0);
    }
  }
  __syncthreads();
  // phase 4: bounce transpose [128 c][40 r] u16 (80B rows)
  {
    int c = wid * 32 + rlo;
    #pragma unroll
    for(int reg = 0; reg < 16; ++reg){
      int r = (reg & 3) + 8 * (reg >> 2) + 4 * (l >> 5);
      *(unsigned short*)(lds + c * 80 + r * 2) = f2b(acc[reg]);
    }
  }
  __syncthreads();
  // phase 5: write Bt: 128 c x 32 r = 512 chunks of 16B
  #pragma unroll
  for(int q = 0; q < 2; ++q){
    int id = q * 256 + t;
    int c = id >> 2, xc = id & 3;
    u16x8 v = *(const u16x8*)(lds + c * 80 + xc * 16);
    *(u16x8*)((char*)Bt + (size_t)c * (NN * 2) + (size_t)r0 * 2 + xc * 16) = v;
  }
}

// ------ main GEMM: BM=256, BN=128, BK=64, 8 waves (64x64 wave tile), KSPLIT=8
//        ring-3 distance-2 pipeline, vmcnt(6) steady state; bf16 partial output ------
__global__ __launch_bounds__(512) void k_gemm(const void* __restrict__ adj_in,
                                              const unsigned short* __restrict__ adjb,
                                              const unsigned short* __restrict__ Bt,
                                              const int* __restrict__ flagp,
                                              unsigned short* __restrict__ partial){
  __shared__ char lds[147456];                // 3 bufs x (A 32KiB + B 16KiB), 128B rows
  const int t = threadIdx.x, wid = t >> 6, l = t & 63;
  const int r0 = blockIdx.x * 256;
  const int kbase = blockIdx.y * 1024;
  const unsigned short* A = (*flagp) ? (const unsigned short*)adj_in : adjb;

  // 6 gld_lds16 per wave per stage (A 4 + B 2), 128-B rows, (row&7)<<4 swizzle
  auto stage = [&](int buf, int kt){
    const int bb = buf * 49152;
    #pragma unroll
    for(int q = 0; q < 4; ++q){               // A: 256 rows x 128B
      int ob = q * 8192 + wid * 1024;
      int o = ob + l * 16;
      int row = o >> 7, x = o & 127;
      gld_lds16((const char*)A + ((size_t)(r0 + row) * NN + kt) * 2
                + (x ^ ((row & 7) << 4)), lds + bb + ob);
    }
    #pragma unroll
    for(int q = 0; q < 2; ++q){               // B: 128 cols x 128B
      int ob = q * 8192 + wid * 1024;
      int o = ob + l * 16;
      int c = o >> 7, x = o & 127;
      gld_lds16((const char*)Bt + ((size_t)c * NN + kt) * 2
                + (x ^ ((c & 7) << 4)), lds + bb + 32768 + ob);
    }
  };

  const int wr = wid >> 1, wc = wid & 1;      // wave tile: 64 rows x 64 cols
  f32x16 acc[2][2];
  #pragma unroll
  for(int a = 0; a < 2; ++a)
    #pragma unroll
    for(int b = 0; b < 2; ++b)
      #pragma unroll
      for(int r2 = 0; r2 < 16; ++r2) acc[a][b][r2] = 0.f;

  const int rlo = l & 31;
  const int swz = (l & 7) << 4;
  const int khalf = (l >> 5) << 4;

  auto compute = [&](int buf){
    const int bb = buf * 49152;
    #pragma unroll
    for(int kk = 0; kk < 4; ++kk){
      int ko = (kk * 32 + khalf) ^ swz;
      bf16x8 a0 = *(const bf16x8*)(lds + bb +         (wr * 64 + rlo)      * 128 + ko);
      bf16x8 a1 = *(const bf16x8*)(lds + bb +         (wr * 64 + rlo + 32) * 128 + ko);
      bf16x8 b0 = *(const bf16x8*)(lds + bb + 32768 + (wc * 64 + rlo)      * 128 + ko);
      bf16x8 b1 = *(const bf16x8*)(lds + bb + 32768 + (wc * 64 + rlo + 32) * 128 + ko);
      acc[0][0] = __builtin_amdgcn_mfma_f32_32x32x16_bf16(a0, b0, acc[0][0], 0, 0, 0);
      acc[0][1] = __builtin_amdgcn_mfma_f32_32x32x16_bf16(a0, b1, acc[0][1], 0, 0, 0);
      acc[1][0] = __builtin_amdgcn_mfma_f32_32x32x16_bf16(a1, b0, acc[1][0], 0, 0, 0);
      acc[1][1] = __builtin_amdgcn_mfma_f32_32x32x16_bf16(a1, b1, acc[1][1], 0, 0, 0);
    }
  };

  stage(0, kbase);
  stage(1, kbase + 64);
  int bc = 0, bs = 2;                          // ring counters
  for(int it = 0; it < 14; ++it){
    asm volatile("s_waitcnt vmcnt(6)" ::: "memory");   // drain own stage-it (1 stage in flight)
    __builtin_amdgcn_s_barrier();
    __builtin_amdgcn_sched_barrier(0);
    stage(bs, kbase + (it + 2) * 64);          // WAR-safe: its readers passed this barrier
    compute(bc);
    bc = (bc == 2) ? 0 : bc + 1;
    bs = (bs == 2) ? 0 : bs + 1;
  }
  asm volatile("s_waitcnt vmcnt(6)" ::: "memory");     // drains stage 14
  __builtin_amdgcn_s_barrier();
  __builtin_amdgcn_sched_barrier(0);
  compute(2);                                  // it=14: buf 14%3=2
  asm volatile("s_waitcnt vmcnt(0)" ::: "memory");
  __builtin_amdgcn_s_barrier();
  __builtin_amdgcn_sched_barrier(0);
  compute(0);                                  // it=15: buf 15%3=0

  unsigned short* pp = partial + ((size_t)blockIdx.y << 20);
  #pragma unroll
  for(int mi = 0; mi < 2; ++mi)
    #pragma unroll
    for(int ni = 0; ni < 2; ++ni)
      #pragma unroll
      for(int reg = 0; reg < 16; ++reg){
        int r = r0 + wr * 64 + mi * 32 + (reg & 3) + 8 * (reg >> 2) + 4 * (l >> 5);
        int c = wc * 64 + ni * 32 + rlo;
        pp[(size_t)r * HID + c] = f2b(acc[mi][ni][reg]);
      }
}

// ------ final epilogue: reduce 8 bf16 partials + norm + bias + softplus -> out ------
__global__ __launch_bounds__(256) void k_out(const unsigned short* __restrict__ partial,
                                             const float* __restrict__ isd,
                                             const void* __restrict__ bsv,
                                             const int* __restrict__ flagp,
                                             void* __restrict__ out){
  const int x = blockIdx.x * 256 + threadIdx.x;
  float v = 0.f;
  #pragma unroll
  for(int p = 0; p < 8; ++p) v += b2f(partial[((size_t)p << 20) + x]);
  const int r = x >> 7, c = x & 127;
  const int mode = *flagp;
  float b = mode ? b2f(((const unsigned short*)bsv)[3 * 128 + c])
                 : ((const float*)bsv)[3 * 128 + c];
  v = v * isd[r] + b;
  float sp = fmaxf(v, 0.f) + log1pf(expf(-fabsf(v)));
  if(mode) ((unsigned short*)out)[x] = f2b(sp);
  else     ((float*)out)[x] = sp;
}

extern "C" void kernel_launch(void* const* d_in, const int* in_sizes, int n_in,
                              void* d_out, int out_size, void* d_ws, size_t ws_size,
                              hipStream_t stream){
  const void* pos = d_in[0];
  const void* emb = d_in[1];
  const void* adj = d_in[2];
  const void* Ws  = d_in[3];
  const void* bs  = d_in[4];

  // ws: flag@0 | isd@0x1000 | Bt@0x210000 (2M) | Wt@0x410000 (128K)
  //     partial@0x430000 (16M bf16) | adjb@0x2430000 (128M)
  char* ws = (char*)d_ws;
  int*            flag    = (int*)(ws);
  float*          isd     = (float*)(ws + 0x1000);
  unsigned short* Bt      = (unsigned short*)(ws + 0x210000);
  unsigned short* Wt      = (unsigned short*)(ws + 0x410000);
  unsigned short* partial = (unsigned short*)(ws + 0x430000);
  unsigned short* adjb    = (unsigned short*)(ws + 0x2430000);

  k_detect<<<1,    256, 0, stream>>>((const unsigned int*)adj, flag);
  k_degcvt<<<2048, 256, 0, stream>>>(adj, flag, isd, adjb);
  k_wt    <<<256,  256, 0, stream>>>(Ws, flag, Wt);

  for(int lyr = 0; lyr < 4; ++lyr){
    if(lyr == 0) k_emb<1><<<256, 256, 0, stream>>>(pos, emb, partial, isd, bs, 0,   flag, Wt, Bt);
    else         k_emb<0><<<256, 256, 0, stream>>>(pos, emb, partial, isd, bs, lyr, flag, Wt, Bt);
    k_gemm<<<dim3(32, 8), 512, 0, stream>>>(adj, adjb, Bt, flag, partial);
  }
  k_out<<<4096, 256, 0, stream>>>(partial, isd, bs, flag, d_out);
}

// Round 15
// 224.995 us; speedup vs baseline: 1.0827x; 1.0163x over previous
//
#include <hip/hip_runtime.h>
#include <hip/hip_bf16.h>
#include <cstdint>

#define NN   8192
#define HID  128

typedef __attribute__((ext_vector_type(8)))  __bf16          bf16x8;
typedef __attribute__((ext_vector_type(16))) float           f32x16;
typedef __attribute__((ext_vector_type(8)))  unsigned short  u16x8;
typedef __attribute__((ext_vector_type(4)))  unsigned short  u16x4;
typedef __attribute__((ext_vector_type(4)))  float           f32x4;

__device__ __forceinline__ float b2f(unsigned short u){
  union { unsigned int i; float f; } v; v.i = ((unsigned int)u) << 16; return v.f;
}
__device__ __forceinline__ unsigned short f2b(float f){
  unsigned int i = __float_as_uint(f);
  unsigned int r = (i + 0x7FFFu + ((i >> 16) & 1u)) >> 16;   // RNE
  return (unsigned short)r;
}
__device__ __forceinline__ void gld_lds16(const void* g, void* l){
  __builtin_amdgcn_global_load_lds((const __attribute__((address_space(1))) unsigned int*)g,
                                   (__attribute__((address_space(3))) unsigned int*)l, 16, 0, 0);
}

// ---- merged pre-pass: dtype detect (per-block, deterministic) + deg/isd +
//      f32->bf16 adj convert + Wt transpose (blocks 0..255) ----
__global__ __launch_bounds__(256) void k_pre(const void* __restrict__ adjv,
                                             const void* __restrict__ Ws,
                                             int* __restrict__ flag,
                                             float* __restrict__ isd,
                                             unsigned short* __restrict__ adjb,
                                             unsigned short* __restrict__ Wt){
  const int t = threadIdx.x, wid = t >> 6, l = t & 63;
  __shared__ int cnt;
  if(t == 0) cnt = 0;
  __syncthreads();
  {
    const unsigned int* a = (const unsigned int*)adjv;
    unsigned int w0 = a[t * 2], w1 = a[t * 2 + 1];
    int c = ((((w0 >> 8) & 0xC0u) == 0u) ? 1 : 0) + ((((w1 >> 8) & 0xC0u) == 0u) ? 1 : 0);
    atomicAdd(&cnt, c);
  }
  __syncthreads();
  const int mode = (cnt > 320) ? 1 : 0;      // bf16 ~512 hits, f32 ~128
  if(t == 0) *flag = mode;                    // all blocks write same value (benign)

  if(blockIdx.x < 256){                       // Wt[l][c][i] = bf16(Ws[l][i][c])
    int x = blockIdx.x * 256 + t;
    int lyr = x >> 14, rem = x & 16383, i = rem >> 7, c = rem & 127;
    unsigned short u = mode ? ((const unsigned short*)Ws)[x]
                            : f2b(((const float*)Ws)[x]);
    Wt[lyr * 16384 + c * 128 + i] = u;
  }

  const int row = blockIdx.x * 4 + wid;
  float s = 0.f;
  if(mode){
    const u16x8* rp = (const u16x8*)((const unsigned short*)adjv + (size_t)row * NN);
    #pragma unroll
    for(int it = 0; it < 16; ++it){
      u16x8 v = rp[it * 64 + l];
      #pragma unroll
      for(int j = 0; j < 8; ++j) s += b2f(v[j]);
    }
  } else {
    const f32x4* rp = (const f32x4*)((const float*)adjv + (size_t)row * NN);
    u16x4* wp = (u16x4*)(adjb + (size_t)row * NN);
    #pragma unroll
    for(int it = 0; it < 32; ++it){
      f32x4 v = rp[it * 64 + l];
      s += v[0] + v[1] + v[2] + v[3];
      u16x4 w;
      w[0] = f2b(v[0]); w[1] = f2b(v[1]); w[2] = f2b(v[2]); w[3] = f2b(v[3]);
      wp[it * 64 + l] = w;
    }
  }
  #pragma unroll
  for(int m = 32; m > 0; m >>= 1) s += __shfl_xor(s, m, 64);
  if(l == 0) isd[row] = (s > 0.f) ? rsqrtf(fmaxf(s, 1e-12f)) : 0.f;
}

// ---- fused epilogue+makeB: 256 blocks x 32 rows. partials are bf16. ----
template<int FIRST>
__global__ __launch_bounds__(256) void k_emb(const void* __restrict__ pos,
                                             const void* __restrict__ emb,
                                             const unsigned short* __restrict__ partial,
                                             const float* __restrict__ isd,
                                             const void* __restrict__ bsv,
                                             int lyr, const int* __restrict__ flagp,
                                             const unsigned short* __restrict__ Wt,
                                             unsigned short* __restrict__ Bt){
  __shared__ char lds[40960];                 // A [0,8K), Wt [8K,40K); bounce reuses [0,10.2K)
  const int t = threadIdx.x, wid = t >> 6, l = t & 63;
  const int r0 = blockIdx.x * 32;
  const int mode = *flagp;

  // phase 1: build A-rows (16 cols per thread), write swizzled bf16 A-tile
  {
    const int r = t >> 3, c0 = (t & 7) * 16;
    const float sc = isd[r0 + r];
    float v[16];
    if(FIRST){
      #pragma unroll
      for(int j = 0; j < 16; ++j){
        int c = c0 + j;
        float x;
        if(mode) x = b2f(c < 3 ? ((const unsigned short*)pos)[(r0 + r) * 3 + c]
                               : ((const unsigned short*)emb)[(r0 + r) * 125 + (c - 3)]);
        else     x = (c < 3) ? ((const float*)pos)[(r0 + r) * 3 + c]
                             : ((const float*)emb)[(r0 + r) * 125 + (c - 3)];
        v[j] = x * sc;
      }
    } else {
      float s[16];
      #pragma unroll
      for(int j = 0; j < 16; ++j) s[j] = 0.f;
      #pragma unroll
      for(int p = 0; p < 8; ++p){
        const unsigned short* pp = partial + ((size_t)p << 20) + (size_t)(r0 + r) * HID + c0;
        u16x8 a0 = *(const u16x8*)pp;
        u16x8 a1 = *(const u16x8*)(pp + 8);
        #pragma unroll
        for(int j = 0; j < 8; ++j){ s[j] += b2f(a0[j]); s[8 + j] += b2f(a1[j]); }
      }
      #pragma unroll
      for(int j = 0; j < 16; ++j){
        float b = mode ? b2f(((const unsigned short*)bsv)[(lyr - 1) * 128 + c0 + j])
                       : ((const float*)bsv)[(lyr - 1) * 128 + c0 + j];
        float h = s[j] * sc + b;
        float sp = fmaxf(h, 0.f) + log1pf(expf(-fabsf(h)));   // stable softplus
        v[j] = sp * sc;                                        // pre-scale for next layer
      }
    }
    u16x8 w0, w1;
    #pragma unroll
    for(int j = 0; j < 8; ++j){ w0[j] = f2b(v[j]); w1[j] = f2b(v[8 + j]); }
    *(u16x8*)(lds + r * 256 + ((c0 * 2)      ^ ((r & 7) << 4))) = w0;
    *(u16x8*)(lds + r * 256 + ((c0 * 2 + 16) ^ ((r & 7) << 4))) = w1;
  }
  // phase 2: stage Wt (128 x 256B) into lds+8192, pre-swizzled source
  {
    const char* Wl = (const char*)(Wt + lyr * 16384);
    #pragma unroll
    for(int q = 0; q < 8; ++q){
      int ob = q * 4096 + wid * 1024;
      int o  = ob + l * 16;
      int c  = o >> 8, x = o & 255;
      gld_lds16(Wl + c * 256 + (x ^ ((c & 7) << 4)), lds + 8192 + ob);
    }
  }
  __syncthreads();
  // phase 3: MFMA — wave w covers B-cols [w*32, w*32+32)
  const int rlo = l & 31;
  f32x16 acc;
  #pragma unroll
  for(int r2 = 0; r2 < 16; ++r2) acc[r2] = 0.f;
  {
    const int swz = (l & 7) << 4;
    #pragma unroll
    for(int s = 0; s < 8; ++s){
      int ko = (s * 32 + ((l >> 5) << 4)) ^ swz;
      bf16x8 a = *(const bf16x8*)(lds + rlo * 256 + ko);
      bf16x8 b = *(const bf16x8*)(lds + 8192 + (wid * 32 + rlo) * 256 + ko);
      acc = __builtin_amdgcn_mfma_f32_32x32x16_bf16(a, b, acc, 0, 0, 0);
    }
  }
  __syncthreads();
  // phase 4: bounce transpose [128 c][40 r] u16 (80B rows)
  {
    int c = wid * 32 + rlo;
    #pragma unroll
    for(int reg = 0; reg < 16; ++reg){
      int r = (reg & 3) + 8 * (reg >> 2) + 4 * (l >> 5);
      *(unsigned short*)(lds + c * 80 + r * 2) = f2b(acc[reg]);
    }
  }
  __syncthreads();
  // phase 5: write Bt: 128 c x 32 r = 512 chunks of 16B
  #pragma unroll
  for(int q = 0; q < 2; ++q){
    int id = q * 256 + t;
    int c = id >> 2, xc = id & 3;
    u16x8 v = *(const u16x8*)(lds + c * 80 + xc * 16);
    *(u16x8*)((char*)Bt + (size_t)c * (NN * 2) + (size_t)r0 * 2 + xc * 16) = v;
  }
}

// ------ main GEMM: BM=256, BN=128, BK=64, 8 waves (64x64 wave tile), KSPLIT=8
//        ring-3 distance-2 pipeline, vmcnt(6) steady state; bf16 partial output ------
__global__ __launch_bounds__(512) void k_gemm(const void* __restrict__ adj_in,
                                              const unsigned short* __restrict__ adjb,
                                              const unsigned short* __restrict__ Bt,
                                              const int* __restrict__ flagp,
                                              unsigned short* __restrict__ partial){
  __shared__ char lds[147456];                // 3 bufs x (A 32KiB + B 16KiB), 128B rows
  const int t = threadIdx.x, wid = t >> 6, l = t & 63;
  const int r0 = blockIdx.x * 256;
  const int kbase = blockIdx.y * 1024;
  const unsigned short* A = (*flagp) ? (const unsigned short*)adj_in : adjb;

  // 6 gld_lds16 per wave per stage (A 4 + B 2), 128-B rows, (row&7)<<4 swizzle
  auto stage = [&](int buf, int kt){
    const int bb = buf * 49152;
    #pragma unroll
    for(int q = 0; q < 4; ++q){               // A: 256 rows x 128B
      int ob = q * 8192 + wid * 1024;
      int o = ob + l * 16;
      int row = o >> 7, x = o & 127;
      gld_lds16((const char*)A + ((size_t)(r0 + row) * NN + kt) * 2
                + (x ^ ((row & 7) << 4)), lds + bb + ob);
    }
    #pragma unroll
    for(int q = 0; q < 2; ++q){               // B: 128 cols x 128B
      int ob = q * 8192 + wid * 1024;
      int o = ob + l * 16;
      int c = o >> 7, x = o & 127;
      gld_lds16((const char*)Bt + ((size_t)c * NN + kt) * 2
                + (x ^ ((c & 7) << 4)), lds + bb + 32768 + ob);
    }
  };

  const int wr = wid >> 1, wc = wid & 1;      // wave tile: 64 rows x 64 cols
  f32x16 acc[2][2];
  #pragma unroll
  for(int a = 0; a < 2; ++a)
    #pragma unroll
    for(int b = 0; b < 2; ++b)
      #pragma unroll
      for(int r2 = 0; r2 < 16; ++r2) acc[a][b][r2] = 0.f;

  const int rlo = l & 31;
  const int swz = (l & 7) << 4;
  const int khalf = (l >> 5) << 4;

  auto compute = [&](int buf){
    const int bb = buf * 49152;
    #pragma unroll
    for(int kk = 0; kk < 4; ++kk){
      int ko = (kk * 32 + khalf) ^ swz;
      bf16x8 a0 = *(const bf16x8*)(lds + bb +         (wr * 64 + rlo)      * 128 + ko);
      bf16x8 a1 = *(const bf16x8*)(lds + bb +         (wr * 64 + rlo + 32) * 128 + ko);
      bf16x8 b0 = *(const bf16x8*)(lds + bb + 32768 + (wc * 64 + rlo)      * 128 + ko);
      bf16x8 b1 = *(const bf16x8*)(lds + bb + 32768 + (wc * 64 + rlo + 32) * 128 + ko);
      acc[0][0] = __builtin_amdgcn_mfma_f32_32x32x16_bf16(a0, b0, acc[0][0], 0, 0, 0);
      acc[0][1] = __builtin_amdgcn_mfma_f32_32x32x16_bf16(a0, b1, acc[0][1], 0, 0, 0);
      acc[1][0] = __builtin_amdgcn_mfma_f32_32x32x16_bf16(a1, b0, acc[1][0], 0, 0, 0);
      acc[1][1] = __builtin_amdgcn_mfma_f32_32x32x16_bf16(a1, b1, acc[1][1], 0, 0, 0);
    }
  };

  stage(0, kbase);
  stage(1, kbase + 64);
  int bc = 0, bs = 2;                          // ring counters
  for(int it = 0; it < 14; ++it){
    asm volatile("s_waitcnt vmcnt(6)" ::: "memory");   // drain own stage-it (1 stage in flight)
    __builtin_amdgcn_s_barrier();
    __builtin_amdgcn_sched_barrier(0);
    stage(bs, kbase + (it + 2) * 64);          // WAR-safe: its readers passed this barrier
    compute(bc);
    bc = (bc == 2) ? 0 : bc + 1;
    bs = (bs == 2) ? 0 : bs + 1;
  }
  asm volatile("s_waitcnt vmcnt(6)" ::: "memory");     // drains stage 14
  __builtin_amdgcn_s_barrier();
  __builtin_amdgcn_sched_barrier(0);
  compute(2);                                  // it=14: buf 14%3=2
  asm volatile("s_waitcnt vmcnt(0)" ::: "memory");
  __builtin_amdgcn_s_barrier();
  __builtin_amdgcn_sched_barrier(0);
  compute(0);                                  // it=15: buf 15%3=0

  unsigned short* pp = partial + ((size_t)blockIdx.y << 20);
  #pragma unroll
  for(int mi = 0; mi < 2; ++mi)
    #pragma unroll
    for(int ni = 0; ni < 2; ++ni)
      #pragma unroll
      for(int reg = 0; reg < 16; ++reg){
        int r = r0 + wr * 64 + mi * 32 + (reg & 3) + 8 * (reg >> 2) + 4 * (l >> 5);
        int c = wc * 64 + ni * 32 + rlo;
        pp[(size_t)r * HID + c] = f2b(acc[mi][ni][reg]);
      }
}

// ------ final epilogue: reduce 8 bf16 partials + norm + bias + softplus -> out ------
__global__ __launch_bounds__(256) void k_out(const unsigned short* __restrict__ partial,
                                             const float* __restrict__ isd,
                                             const void* __restrict__ bsv,
                                             const int* __restrict__ flagp,
                                             void* __restrict__ out){
  const int x = blockIdx.x * 256 + threadIdx.x;
  float v = 0.f;
  #pragma unroll
  for(int p = 0; p < 8; ++p) v += b2f(partial[((size_t)p << 20) + x]);
  const int r = x >> 7, c = x & 127;
  const int mode = *flagp;
  float b = mode ? b2f(((const unsigned short*)bsv)[3 * 128 + c])
                 : ((const float*)bsv)[3 * 128 + c];
  v = v * isd[r] + b;
  float sp = fmaxf(v, 0.f) + log1pf(expf(-fabsf(v)));
  if(mode) ((unsigned short*)out)[x] = f2b(sp);
  else     ((float*)out)[x] = sp;
}

extern "C" void kernel_launch(void* const* d_in, const int* in_sizes, int n_in,
                              void* d_out, int out_size, void* d_ws, size_t ws_size,
                              hipStream_t stream){
  const void* pos = d_in[0];
  const void* emb = d_in[1];
  const void* adj = d_in[2];
  const void* Ws  = d_in[3];
  const void* bs  = d_in[4];

  // ws: flag@0 | isd@0x1000 | Bt@0x210000 (2M) | Wt@0x410000 (128K)
  //     partial@0x430000 (16M bf16) | adjb@0x2430000 (128M)
  char* ws = (char*)d_ws;
  int*            flag    = (int*)(ws);
  float*          isd     = (float*)(ws + 0x1000);
  unsigned short* Bt      = (unsigned short*)(ws + 0x210000);
  unsigned short* Wt      = (unsigned short*)(ws + 0x410000);
  unsigned short* partial = (unsigned short*)(ws + 0x430000);
  unsigned short* adjb    = (unsigned short*)(ws + 0x2430000);

  k_pre<<<2048, 256, 0, stream>>>(adj, Ws, flag, isd, adjb, Wt);

  for(int lyr = 0; lyr < 4; ++lyr){
    if(lyr == 0) k_emb<1><<<256, 256, 0, stream>>>(pos, emb, partial, isd, bs, 0,   flag, Wt, Bt);
    else         k_emb<0><<<256, 256, 0, stream>>>(pos, emb, partial, isd, bs, lyr, flag, Wt, Bt);
    k_gemm<<<dim3(32, 8), 512, 0, stream>>>(adj, adjb, Bt, flag, partial);
  }
  k_out<<<4096, 256, 0, stream>>>(partial, isd, bs, flag, d_out);
}